// Round 4
// baseline (6273.196 us; speedup 1.0000x reference)
//
#include <hip/hip_runtime.h>

// Problem dims (fixed by setup_inputs)
#define B_  4
#define L_  2048
#define D_  2048
#define R_  2560
#define BL_ (B_ * L_)
#define LP_ (L_ + 6)          // padded L for conv shifts (3 each side)

#define CHK_  16              // scan chunks along L
#define CLEN_ (L_ / CHK_)     // 128

typedef unsigned short u16;
typedef unsigned int   u32;

typedef __attribute__((ext_vector_type(8))) short short8;
typedef __attribute__((ext_vector_type(4))) float f32x4;

static __device__ __forceinline__ u16 f2bf(float f) {
  u32 x = __float_as_uint(f);
  x += 0x7fffu + ((x >> 16) & 1u);   // round-to-nearest-even
  return (u16)(x >> 16);
}
static __device__ __forceinline__ float bf2f(u16 u) {
  return __uint_as_float(((u32)u) << 16);
}

// async global->LDS, 16B per lane; LDS dest = wave-uniform base + lane*16
static __device__ __forceinline__ void gld16(const u16* g, u16* l) {
  __builtin_amdgcn_global_load_lds(
      (const __attribute__((address_space(1))) void*)g,
      (__attribute__((address_space(3))) void*)l, 16, 0, 0);
}

#define SB0()     __builtin_amdgcn_sched_barrier(0)
#define BAR()     __builtin_amdgcn_s_barrier()
#define LGKM0()   do { asm volatile("s_waitcnt lgkmcnt(0)" ::: "memory"); SB0(); } while (0)

// ---------------- conversions ----------------
__global__ void cvt_bf16(const float* __restrict__ src, u16* __restrict__ dst, int n) {
  int i = blockIdx.x * blockDim.x + threadIdx.x;
  int stride = gridDim.x * blockDim.x;
  for (; i < n; i += stride) dst[i] = f2bf(src[i]);
}

// conv_w [R,R,4] fp32 -> 4 planes of [R,R] bf16 (tap-major)
__global__ void cvt_convw(const float* __restrict__ cw, u16* __restrict__ out) {
  int i = blockIdx.x * blockDim.x + threadIdx.x;  // over R_*R_ (o*R + iin)
  if (i >= R_ * R_) return;
  const float4 v = *(const float4*)(cw + (size_t)i * 4);
  out[(size_t)0 * R_ * R_ + i] = f2bf(v.x);
  out[(size_t)1 * R_ * R_ + i] = f2bf(v.y);
  out[(size_t)2 * R_ * R_ + i] = f2bf(v.z);
  out[(size_t)3 * R_ * R_ + i] = f2bf(v.w);
}

// zero the 3+3 pad rows per batch of padded h1 [B][LP_][R]
__global__ void zero_pads(u16* __restrict__ h1p) {
  int i = blockIdx.x * blockDim.x + threadIdx.x;   // over 24*R_
  if (i >= 24 * R_) return;
  const int rr = i / R_, c = i % R_;
  const int b = rr / 6, k = rr % 6;
  const int row = b * LP_ + (k < 3 ? k : L_ + k);  // rows 0..2 and 2051..2053
  h1p[(size_t)row * R_ + c] = 0;
}

// ---------------- 256-wide pipelined 4-phase GEMM ----------------
// C[M, N] = act(A[M,K] * Bm[N,K]^T + bias[N]), bf16 in, fp32 accum.
// BM=256, BN=NF*64 (NF=5 -> 320, NF=4 -> 256), BK=64. 512 threads = 8 waves (2M x 4N).
// Per wave: 128 rows x NF*16 cols = acc[8][NF].
//
// SOFTWARE-PIPELINED PHASES (the r3 fix): each phase's ds_reads are issued one phase
// EARLY, into ping-pong register sets, so they stream during the previous phase's MFMA
// block. One barrier per phase (4/tile, was 8). Phase body:
//   BAR; lgkmcnt(0)+SB0      // reads for THIS phase (issued last segment) complete
//   issue reads for NEXT phase -> other reg set; SB0
//   setprio(1); 4*NF MFMA; setprio(0)
//   [stages]; [vmcnt]; SB0
// Reg sets: aX/aY ping-pong per phase; bX covers {ph0,ph1} (k0), bY {ph2,ph3} (k1).
//   ph0: use(aX,bX) issue aY<-A(h1,k0);            stage A1(t+1)->lds[p^1].h1
//   ph1: use(aY,bX) issue aX<-A(h0,k1), bY<-B(k1)
//   ph2: use(aX,bY) issue aY<-A(h1,k1);            vmcnt(2)
//   ph3: use(aY,bY) issue aX<-A'(h0,k0), bX<-B'(k0) from lds[p^1];
//        stage A0(t+2)+B(t+2)->lds[p];             vmcnt(NF+2)
// Safety audit (segment-granular, barriers between):
//  - stage targets disjoint from same-segment read targets (ph0: p^1.h1 vs p.h1; ph3:
//    p.h0+B vs p^1) and only overwrite regions whose last read completed >=1 barrier ago.
//  - cross-wave staged-data visibility: vmcnt(2)@ph2 (retires t+1's A0/B batch) + BAR_ph3
//    guards the ph3-tail reads of lds[p^1]; vmcnt(NF+2)@ph3 (retires A1 batch) + BAR_ph0
//    guards ph0-tail reads. Outstanding oscillates NF+2 <-> NF+4; both waits target loads
//    issued >=3 segments prior => no stall.
// LDS per buffer: A halves [128][64] + NF B chunks [64][64], 128B rows, chunk-XOR swizzle
// c^(row&7) on stage SOURCE and ds_read (both-sides rule). Conflicts measured 0.
// amdgpu_waves_per_eu(2,2): 256 VGPR/wave budget (r1/r2: default 4 waves/EU = 128 VGPR
// spilled the accumulator). #pragma unroll 1 on t-loop keeps pressure flat.
template <int NF, int IB>
__device__ __forceinline__ void mfma_block(f32x4 (&acc)[8][NF], const short8 (&aF)[4],
                                           const short8 (&bF)[NF]) {
#pragma unroll
  for (int i = 0; i < 4; ++i)
#pragma unroll
    for (int j = 0; j < NF; ++j)
      acc[IB + i][j] =
          __builtin_amdgcn_mfma_f32_16x16x32_bf16(aF[i], bF[j], acc[IB + i][j], 0, 0, 0);
}

template <int KDIM, int TAPS, int NF, int ACT, int OBF16, int PADOUT>
__global__ __launch_bounds__(512)
__attribute__((amdgpu_waves_per_eu(2, 2)))
void gemm256(const u16* __restrict__ A, const u16* __restrict__ Bm,
             const float* __restrict__ bias, void* __restrict__ Cv, int N) {
  constexpr int NTK = KDIM / 64;
  constexpr int NT  = NTK * TAPS;
  constexpr int BN  = NF * 64;
  constexpr int BUFU16 = 16384 + NF * 4096;      // u16 per buffer (A 32KB + B NF*8KB)
  __shared__ u16 lds[2][BUFU16];

  const int tid  = threadIdx.x;
  const int wave = tid >> 6, lane = tid & 63;
  const int wr = wave >> 2, wc = wave & 3;       // 2 x 4 wave grid
  const int q = lane >> 4, r16 = lane & 15;
  const int rsw = r16 & 7;
  const int bm = blockIdx.x * 256, bn = blockIdx.y * BN;
  const int srow = tid >> 3;                     // 0..63 staging row
  const int schunk = (tid & 7) ^ (srow & 7);     // pre-swizzled source chunk
  const int bbatch = bm >> 11;                   // batch (L_=2048, BM=256 divides)
  const int arow0 = (TAPS == 4) ? (bm + 3 + 6 * bbatch) : bm;

  f32x4 acc[8][NF] = {};

  auto stA = [&](int u, int h) {                 // one A half-tile (128 rows): 2 issues
    const int uc = (u < NT) ? u : (NT - 1);
    const int tap = uc / NTK;
    const int ku  = (uc % NTK) * 64;
    const int sh  = (TAPS == 4) ? (2 * tap - 3) : 0;
    const u16* src = A + (size_t)(arow0 + sh + h * 128) * KDIM + ku + schunk * 8;
    u16* dst = &lds[u & 1][h * 8192 + wave * 512];
#pragma unroll
    for (int s = 0; s < 2; ++s)
      gld16(src + (size_t)(s * 64 + srow) * KDIM, dst + s * 4096);
  };
  auto stB = [&](int u, int j) {                 // one B chunk (64 N-rows): 1 issue
    const int uc = (u < NT) ? u : (NT - 1);
    const int tap = uc / NTK;
    const int ku  = (uc % NTK) * 64;
    const u16* src = Bm + (size_t)tap * R_ * R_ +
                     (size_t)(bn + j * 64 + srow) * KDIM + ku + schunk * 8;
    gld16(src, &lds[u & 1][16384 + j * 4096 + wave * 512]);
  };
  auto ldA = [&](short8 (&f)[4], int p, int half, int k) {
    const int base = half * 8192 + (wr * 64 + r16) * 64 + ((k * 4 + q) ^ rsw) * 8;
#pragma unroll
    for (int i = 0; i < 4; ++i)
      f[i] = *(const short8*)&lds[p][base + i * 1024];
  };
  auto ldB = [&](short8 (&f)[NF], int p, int k) {
    const int base = 16384 + (wc * 16 + r16) * 64 + ((k * 4 + q) ^ rsw) * 8;
#pragma unroll
    for (int j = 0; j < NF; ++j)
      f[j] = *(const short8*)&lds[p][base + j * 4096];
  };

  // ---- prologue: tile0 fully + tile1's A0 and B; A1(1) arrives via t=0 ph0 stage
  stA(0, 0); stA(0, 1);
#pragma unroll
  for (int j = 0; j < NF; ++j) stB(0, j);
  stA(1, 0);
#pragma unroll
  for (int j = 0; j < NF; ++j) stB(1, j);
  asm volatile("s_waitcnt vmcnt(%0)" :: "n"(NF + 2) : "memory");  // tile0 resident
  SB0();
  BAR();

  short8 aX[4], aY[4], bX[NF], bY[NF];
  // initial reads for t=0 ph0
  ldA(aX, 0, 0, 0);
  ldB(bX, 0, 0);
  SB0();

#pragma unroll 1
  for (int t = 0; t < NT; ++t) {
    const int p = t & 1;
    // ---- phase 0: MFMA(h0,k0); prefetch-reads A(h1,k0); stage A1(t+1)
    BAR(); LGKM0();
    ldA(aY, p, 1, 0);
    SB0();
    __builtin_amdgcn_s_setprio(1);
    mfma_block<NF, 0>(acc, aX, bX);
    __builtin_amdgcn_s_setprio(0);
    stA(t + 1, 1);
    SB0();
    // ---- phase 1: MFMA(h1,k0); prefetch-reads A(h0,k1), B(k1)
    BAR(); LGKM0();
    ldA(aX, p, 0, 1);
    ldB(bY, p, 1);
    SB0();
    __builtin_amdgcn_s_setprio(1);
    mfma_block<NF, 4>(acc, aY, bX);
    __builtin_amdgcn_s_setprio(0);
    SB0();
    // ---- phase 2: MFMA(h0,k1); prefetch-reads A(h1,k1); vmcnt(2) (t+1 A0/B resident)
    BAR(); LGKM0();
    ldA(aY, p, 1, 1);
    SB0();
    __builtin_amdgcn_s_setprio(1);
    mfma_block<NF, 0>(acc, aX, bY);
    __builtin_amdgcn_s_setprio(0);
    asm volatile("s_waitcnt vmcnt(2)" ::: "memory");
    SB0();
    // ---- phase 3: MFMA(h1,k1); prefetch-reads next tile (h0,k0),B(k0) from lds[p^1];
    //               stage A0(t+2)+B(t+2) into now-dead regions of lds[p]; vmcnt(NF+2)
    BAR(); LGKM0();
    ldA(aX, p ^ 1, 0, 0);
    ldB(bX, p ^ 1, 0);
    SB0();
    __builtin_amdgcn_s_setprio(1);
    mfma_block<NF, 4>(acc, aY, bY);
    __builtin_amdgcn_s_setprio(0);
    stA(t + 2, 0);
#pragma unroll
    for (int j = 0; j < NF; ++j) stB(t + 2, j);
    asm volatile("s_waitcnt vmcnt(%0)" :: "n"(NF + 2) : "memory");
    SB0();
  }

  // ---- epilogue
#pragma unroll
  for (int i = 0; i < 8; ++i) {
    const int rb  = ((i & 4) ? 128 : 0) + wr * 64 + (i & 3) * 16;
    const int row = bm + rb + q * 4;
    const int orow = PADOUT ? (row + 3 + 6 * bbatch) : row;
#pragma unroll
    for (int j = 0; j < NF; ++j) {
      const int col = bn + j * 64 + wc * 16 + r16;
      const float bv = bias[col];
#pragma unroll
      for (int rr = 0; rr < 4; ++rr) {
        float v = acc[i][j][rr] + bv;
        if (ACT == 1) v = v / (1.f + __expf(-v));
        const size_t off = (size_t)(orow + rr) * N + col;
        if (OBF16) ((u16*)Cv)[off] = f2bf(v);
        else       ((float*)Cv)[off] = v;
      }
    }
  }
}

// ---------------- RG-LRU elementwise: build (a, b) fp32 ----------------
__global__ void gate_ew(const u16* __restrict__ gab, const u16* __restrict__ gib,
                        const u16* __restrict__ h2b, const float* __restrict__ lam,
                        float* __restrict__ a32, float* __restrict__ b32) {
  int idx = blockIdx.x * blockDim.x + threadIdx.x;
  if (idx >= BL_ * R_) return;
  const int r = idx % R_;
  const float ga = bf2f(gab[idx]);
  const float gi = bf2f(gib[idx]);
  const float h2 = bf2f(h2b[idx]);
  const float rr = 1.f / (1.f + __expf(-ga));
  const float ii = 1.f / (1.f + __expf(-gi));
  const float lm = lam[r];
  const float sp = log1pf(__expf(lm));          // softplus, lam in [0.5,2]
  const float log_a = -8.f * rr * sp;
  const float a  = __expf(log_a);
  const float e2 = __expf(2.f * log_a);
  const float mult = sqrtf(fmaxf(1.f - e2, 0.f));
  a32[idx] = a;
  b32[idx] = mult * ii * h2;
}

// ---------------- chunked scan: 3 passes ----------------
__global__ void scan_pass1(const float* __restrict__ a32, const float* __restrict__ b32,
                           float* __restrict__ Aprod, float* __restrict__ Hend) {
  int t = blockIdx.x * blockDim.x + threadIdx.x;   // over CHK_*B_*R_
  if (t >= CHK_ * B_ * R_) return;
  const int c = t / (B_ * R_), br = t % (B_ * R_);
  const int b = br / R_, r = br % R_;
  size_t idx = ((size_t)b * L_ + c * CLEN_) * R_ + r;
  float Ap = 1.f, h = 0.f;
  for (int l = 0; l < CLEN_; ++l) {
    const float a = a32[idx], bb = b32[idx];
    Ap *= a;
    h = a * h + bb;
    idx += R_;
  }
  Aprod[t] = Ap;
  Hend[t]  = h;
}

__global__ void scan_pass2(const float* __restrict__ Aprod, float* __restrict__ Hend) {
  int br = blockIdx.x * blockDim.x + threadIdx.x;
  if (br >= B_ * R_) return;
  float h = Hend[br];                               // chunk 0 end state
  for (int c = 1; c < CHK_; ++c) {
    const int i = c * (B_ * R_) + br;
    h = Hend[i] + Aprod[i] * h;
    Hend[i] = h;
  }
}

__global__ void scan_pass3(const float* __restrict__ a32, const float* __restrict__ b32,
                           const float* __restrict__ Hend, u16* __restrict__ hs) {
  int t = blockIdx.x * blockDim.x + threadIdx.x;
  if (t >= CHK_ * B_ * R_) return;
  const int c = t / (B_ * R_), br = t % (B_ * R_);
  const int b = br / R_, r = br % R_;
  float h = (c == 0) ? 0.f : Hend[(size_t)(c - 1) * (B_ * R_) + br];
  size_t idx = ((size_t)b * L_ + c * CLEN_) * R_ + r;
  for (int l = 0; l < CLEN_; ++l) {
    h = a32[idx] * h + b32[idx];
    hs[idx] = f2bf(h);
    idx += R_;
  }
}

// ---------------- launcher ----------------
extern "C" void kernel_launch(void* const* d_in, const int* in_sizes, int n_in,
                              void* d_out, int out_size, void* d_ws, size_t ws_size,
                              hipStream_t stream) {
  (void)in_sizes; (void)n_in; (void)out_size; (void)ws_size;
  const float* x   = (const float*)d_in[0];
  const float* w1  = (const float*)d_in[1];
  const float* b1  = (const float*)d_in[2];
  const float* cw  = (const float*)d_in[3];
  const float* cb  = (const float*)d_in[4];
  const float* wa  = (const float*)d_in[5];
  const float* ba  = (const float*)d_in[6];
  const float* wx  = (const float*)d_in[7];
  const float* bx  = (const float*)d_in[8];
  const float* lam = (const float*)d_in[9];
  const float* w2  = (const float*)d_in[10];
  const float* b2  = (const float*)d_in[11];

  char* ws = (char*)d_ws;
  size_t o = 0;
  auto alloc = [&](size_t bytes) { char* p = ws + o; o += (bytes + 255) & ~255ull; return p; };

  u16* w2b = (u16*)alloc((size_t)D_ * R_ * 2);
  u16* wab = (u16*)alloc((size_t)R_ * R_ * 2);
  u16* wxb = (u16*)alloc((size_t)R_ * R_ * 2);
  char* a32p = ws + o;                       // overlay: xb+w1b+cwb (dead by then) = 96.5MB >= 84MB
  u16* xb  = (u16*)alloc((size_t)BL_ * D_ * 2);
  u16* w1b = (u16*)alloc((size_t)R_ * D_ * 2);
  u16* cwb = (u16*)alloc((size_t)4 * R_ * R_ * 2);
  char* b32p = ws + o;                       // overlay: h1p (dead after conv) + extra = 84MB
  u16* h1p = (u16*)alloc((size_t)B_ * LP_ * R_ * 2);          // padded h1
  alloc((size_t)BL_ * R_ * 4 - (size_t)B_ * LP_ * R_ * 2);    // extra tail of b32 overlay
  u16* h2b = (u16*)alloc((size_t)BL_ * R_ * 2);
  u16* gab = (u16*)alloc((size_t)BL_ * R_ * 2);
  u16* gib = (u16*)alloc((size_t)BL_ * R_ * 2);
  float* Aprod = (float*)alloc((size_t)CHK_ * B_ * R_ * 4);
  float* Hend  = (float*)alloc((size_t)CHK_ * B_ * R_ * 4);
  float* a32 = (float*)a32p;
  float* b32 = (float*)b32p;
  u16* hsb = gab;                            // reuse after gate_ew consumed it

  cvt_bf16<<<4096, 256, 0, stream>>>(x,  xb,  BL_ * D_);
  cvt_bf16<<<2048, 256, 0, stream>>>(w1, w1b, R_ * D_);
  cvt_bf16<<<2048, 256, 0, stream>>>(wa, wab, R_ * R_);
  cvt_bf16<<<2048, 256, 0, stream>>>(wx, wxb, R_ * R_);
  cvt_bf16<<<2048, 256, 0, stream>>>(w2, w2b, D_ * R_);
  cvt_convw<<<(R_ * R_ + 255) / 256, 256, 0, stream>>>(cw, cwb);
  zero_pads<<<(24 * R_ + 255) / 256, 256, 0, stream>>>(h1p);

  // linear1 + silu -> padded h1 (rows +3+6*batch)
  gemm256<2048, 1, 5, 1, 1, 1><<<dim3(32, 8), 512, 0, stream>>>(xb, w1b, b1, h1p, R_);
  // temporal conv: K' = 4*R GEMM over padded h1 (tap folded into K-tiles)
  gemm256<2560, 4, 5, 0, 1, 0><<<dim3(32, 8), 512, 0, stream>>>(h1p, cwb, cb, h2b, R_);
  // gates
  gemm256<2560, 1, 5, 0, 1, 0><<<dim3(32, 8), 512, 0, stream>>>(h2b, wab, ba, gab, R_);
  gemm256<2560, 1, 5, 0, 1, 0><<<dim3(32, 8), 512, 0, stream>>>(h2b, wxb, bx, gib, R_);
  // a,b for recurrence
  gate_ew<<<(BL_ * R_ + 255) / 256, 256, 0, stream>>>(gab, gib, h2b, lam, a32, b32);
  // linear recurrence (chunked, 3 passes)
  scan_pass1<<<(CHK_ * B_ * R_ + 255) / 256, 256, 0, stream>>>(a32, b32, Aprod, Hend);
  scan_pass2<<<(B_ * R_ + 255) / 256, 256, 0, stream>>>(Aprod, Hend);
  scan_pass3<<<(CHK_ * B_ * R_ + 255) / 256, 256, 0, stream>>>(a32, b32, Hend, hsb);
  // linear2 -> d_out (fp32), N=2048 uses NF=4 (grid 32x8 exact)
  gemm256<2560, 1, 4, 0, 0, 0><<<dim3(32, 8), 512, 0, stream>>>(hsb, w2b, b2, d_out, D_);
}

// Round 5
// 1347.439 us; speedup vs baseline: 4.6556x; 4.6556x over previous
//
#include <hip/hip_runtime.h>

// Problem dims (fixed by setup_inputs)
#define B_  4
#define L_  2048
#define D_  2048
#define R_  2560
#define BL_ (B_ * L_)
#define LP_ (L_ + 6)          // padded L for conv shifts (3 each side)

#define CHK_  16              // scan chunks along L
#define CLEN_ (L_ / CHK_)     // 128

typedef unsigned short u16;
typedef unsigned int   u32;

typedef __attribute__((ext_vector_type(8))) short short8;
typedef __attribute__((ext_vector_type(4))) float f32x4;

static __device__ __forceinline__ u16 f2bf(float f) {
  u32 x = __float_as_uint(f);
  x += 0x7fffu + ((x >> 16) & 1u);   // round-to-nearest-even
  return (u16)(x >> 16);
}
static __device__ __forceinline__ float bf2f(u16 u) {
  return __uint_as_float(((u32)u) << 16);
}

// async global->LDS, 16B per lane; LDS dest = wave-uniform base + lane*16
static __device__ __forceinline__ void gld16(const u16* g, u16* l) {
  __builtin_amdgcn_global_load_lds(
      (const __attribute__((address_space(1))) void*)g,
      (__attribute__((address_space(3))) void*)l, 16, 0, 0);
}

#define SB0()     __builtin_amdgcn_sched_barrier(0)
#define BAR()     __builtin_amdgcn_s_barrier()
#define LGKM0()   do { asm volatile("s_waitcnt lgkmcnt(0)" ::: "memory"); SB0(); } while (0)

// ---------------- conversions ----------------
__global__ void cvt_bf16(const float* __restrict__ src, u16* __restrict__ dst, int n) {
  int i = blockIdx.x * blockDim.x + threadIdx.x;
  int stride = gridDim.x * blockDim.x;
  for (; i < n; i += stride) dst[i] = f2bf(src[i]);
}

// conv_w [R,R,4] fp32 -> 4 planes of [R,R] bf16 (tap-major)
__global__ void cvt_convw(const float* __restrict__ cw, u16* __restrict__ out) {
  int i = blockIdx.x * blockDim.x + threadIdx.x;  // over R_*R_ (o*R + iin)
  if (i >= R_ * R_) return;
  const float4 v = *(const float4*)(cw + (size_t)i * 4);
  out[(size_t)0 * R_ * R_ + i] = f2bf(v.x);
  out[(size_t)1 * R_ * R_ + i] = f2bf(v.y);
  out[(size_t)2 * R_ * R_ + i] = f2bf(v.z);
  out[(size_t)3 * R_ * R_ + i] = f2bf(v.w);
}

// zero the 3+3 pad rows per batch of padded h1 [B][LP_][R]
__global__ void zero_pads(u16* __restrict__ h1p) {
  int i = blockIdx.x * blockDim.x + threadIdx.x;   // over 24*R_
  if (i >= 24 * R_) return;
  const int rr = i / R_, c = i % R_;
  const int b = rr / 6, k = rr % 6;
  const int row = b * LP_ + (k < 3 ? k : L_ + k);  // rows 0..2 and 2051..2053
  h1p[(size_t)row * R_ + c] = 0;
}

// concat gate biases [ba | bx] -> bcat[2R]
__global__ void cat_bias(const float* __restrict__ ba, const float* __restrict__ bx,
                         float* __restrict__ bcat) {
  int i = blockIdx.x * blockDim.x + threadIdx.x;
  if (i < R_) bcat[i] = ba[i];
  else if (i < 2 * R_) bcat[i] = bx[i - R_];
}

// ---------------- 256x256 pipelined 4-phase GEMM (NF=4, m201 geometry) ----------------
// C[M, N] = act(A[M,K] * Bm[N,K]^T + bias[N]), bf16 in, fp32 accum.
// BM=BN=256, BK=64. 512 threads = 8 waves (2M x 4N). Per wave 128x64 = acc[8][4] (128
// regs, lives in AGPRs; unified-file budget 256/wave at 2 waves/SIMD). NF=5 (acc 160)
// was on the register cliff (r1/r2/r4 spilled, WRITE_SIZE 41MB->637MB/7GB); NF=4 is the
// proven m201 shape. LDS = 2 x (A 32KB + B 32KB) = 128 KB -> 1 WG/CU, 8 waves.
//
// Phase structure IDENTICAL to r3 (the only non-spilling verified schedule):
//   ph0: ds_read A(h0,k0)+B(k0)->bF; stage A1(t+1)->lds[p^1].h1 ; BAR;LGKM0; MFMA acc[0..3]
//   ph1: ds_read A(h1,k0)                                       ; BAR;LGKM0; MFMA acc[4..7]
//   ph2: ds_read A(h0,k1)+B(k1)->bF                             ; BAR;LGKM0; MFMA acc[0..3]
//   ph3: ds_read A(h1,k1); stage A0(t+2)+B(t+2)->lds[p]         ; BAR;LGKM0; MFMA acc[4..7];
//        vmcnt(6)
// vmcnt audit: outstanding at ph3 end = 2 (ph0: A1(t+1)) + 6 (ph3: A0/B(t+2));
// vmcnt(6) retires the ph0 pair (issued 3 phases earlier -> no stall); older batches
// already retired by the previous tile's vmcnt. Each staged region is guarded by
// vmcnt + one barrier before any wave reads it. Stage targets are disjoint from
// same-phase read regions (ph0: p^1.h1 vs p.h0/B; ph3: p.h0+B vs p.h1).
// Chunk-XOR swizzle c^(row&7) on stage SOURCE and ds_read (both-sides rule);
// bank conflicts measured 0.
//
// Grid is 1-D (nwg % 8 == 0) with XCD-chunked swizzle: each XCD gets a contiguous
// range of work ids; x-major decomposition makes consecutive ids share the B panel.
template <int NF, int IB>
__device__ __forceinline__ void mfma_block(f32x4 (&acc)[8][NF], const short8 (&aF)[4],
                                           const short8 (&bF)[NF]) {
#pragma unroll
  for (int i = 0; i < 4; ++i)
#pragma unroll
    for (int j = 0; j < NF; ++j)
      acc[IB + i][j] =
          __builtin_amdgcn_mfma_f32_16x16x32_bf16(aF[i], bF[j], acc[IB + i][j], 0, 0, 0);
}

template <int KDIM, int TAPS, int ACT, int OBF16, int PADOUT>
__global__ __launch_bounds__(512)
__attribute__((amdgpu_waves_per_eu(2, 2)))
void gemm256(const u16* __restrict__ A, const u16* __restrict__ Bm,
             const float* __restrict__ bias, void* __restrict__ Cv, int N, int NBX) {
  constexpr int NF  = 4;
  constexpr int NTK = KDIM / 64;
  constexpr int NT  = NTK * TAPS;
  constexpr int BUFU16 = 16384 + NF * 4096;      // u16 per buffer (A 32KB + B 32KB)
  __shared__ u16 lds[2][BUFU16];

  // XCD-chunked bijective swizzle (requires gridDim.x % 8 == 0)
  const int cpx = gridDim.x >> 3;
  int lin = blockIdx.x;
  lin = (lin & 7) * cpx + (lin >> 3);
  const int bx = lin % NBX, by = lin / NBX;

  const int tid  = threadIdx.x;
  const int wave = tid >> 6, lane = tid & 63;
  const int wr = wave >> 2, wc = wave & 3;       // 2 x 4 wave grid
  const int q = lane >> 4, r16 = lane & 15;
  const int rsw = r16 & 7;
  const int bm = bx * 256, bn = by * 256;
  const int srow = tid >> 3;                     // 0..63 staging row
  const int schunk = (tid & 7) ^ (srow & 7);     // pre-swizzled source chunk
  const int bbatch = bm >> 11;                   // batch (L_=2048, BM=256 divides)
  const int arow0 = (TAPS == 4) ? (bm + 3 + 6 * bbatch) : bm;

  f32x4 acc[8][NF] = {};

  auto stA = [&](int u, int h) {                 // one A half-tile (128 rows): 2 issues
    const int uc = (u < NT) ? u : (NT - 1);
    const int tap = uc / NTK;
    const int ku  = (uc % NTK) * 64;
    const int sh  = (TAPS == 4) ? (2 * tap - 3) : 0;
    const u16* src = A + (size_t)(arow0 + sh + h * 128) * KDIM + ku + schunk * 8;
    u16* dst = &lds[u & 1][h * 8192 + wave * 512];
#pragma unroll
    for (int s = 0; s < 2; ++s)
      gld16(src + (size_t)(s * 64 + srow) * KDIM, dst + s * 4096);
  };
  auto stB = [&](int u, int j) {                 // one B chunk (64 N-rows): 1 issue
    const int uc = (u < NT) ? u : (NT - 1);
    const int tap = uc / NTK;
    const int ku  = (uc % NTK) * 64;
    const u16* src = Bm + (size_t)tap * R_ * R_ +
                     (size_t)(bn + j * 64 + srow) * KDIM + ku + schunk * 8;
    gld16(src, &lds[u & 1][16384 + j * 4096 + wave * 512]);
  };
  auto ldA = [&](short8 (&f)[4], int p, int half, int k) {
    const int base = half * 8192 + (wr * 64 + r16) * 64 + ((k * 4 + q) ^ rsw) * 8;
#pragma unroll
    for (int i = 0; i < 4; ++i)
      f[i] = *(const short8*)&lds[p][base + i * 1024];
  };
  auto ldB = [&](short8 (&f)[NF], int p, int k) {
    const int base = 16384 + (wc * 16 + r16) * 64 + ((k * 4 + q) ^ rsw) * 8;
#pragma unroll
    for (int j = 0; j < NF; ++j)
      f[j] = *(const short8*)&lds[p][base + j * 4096];
  };

  // ---- prologue: tile0 fully + tile1's A0 and B; A1(1) arrives via t=0 ph0 stage
  stA(0, 0); stA(0, 1);
#pragma unroll
  for (int j = 0; j < NF; ++j) stB(0, j);
  stA(1, 0);
#pragma unroll
  for (int j = 0; j < NF; ++j) stB(1, j);
  asm volatile("s_waitcnt vmcnt(%0)" :: "n"(NF + 2) : "memory");  // tile0 resident
  SB0();
  BAR();

  short8 aF[4], bF[NF];
  for (int t = 0; t < NT; ++t) {
    const int p = t & 1;
    // ---- phase 0: M-half0 x k0; stage A1(t+1)
    ldA(aF, p, 0, 0);
    ldB(bF, p, 0);
    stA(t + 1, 1);
    BAR(); LGKM0();
    __builtin_amdgcn_s_setprio(1);
    mfma_block<NF, 0>(acc, aF, bF);
    __builtin_amdgcn_s_setprio(0);
    SB0(); BAR();
    // ---- phase 1: M-half1 x k0 (reuses bF)
    ldA(aF, p, 1, 0);
    BAR(); LGKM0();
    __builtin_amdgcn_s_setprio(1);
    mfma_block<NF, 4>(acc, aF, bF);
    __builtin_amdgcn_s_setprio(0);
    SB0(); BAR();
    // ---- phase 2: M-half0 x k1 (reloads bF)
    ldA(aF, p, 0, 1);
    ldB(bF, p, 1);
    BAR(); LGKM0();
    __builtin_amdgcn_s_setprio(1);
    mfma_block<NF, 0>(acc, aF, bF);
    __builtin_amdgcn_s_setprio(0);
    SB0(); BAR();
    // ---- phase 3: M-half1 x k1; stage A0(t+2)+B(t+2) into now-dead regions of lds[p]
    ldA(aF, p, 1, 1);
    stA(t + 2, 0);
#pragma unroll
    for (int j = 0; j < NF; ++j) stB(t + 2, j);
    BAR(); LGKM0();
    __builtin_amdgcn_s_setprio(1);
    mfma_block<NF, 4>(acc, aF, bF);
    __builtin_amdgcn_s_setprio(0);
    asm volatile("s_waitcnt vmcnt(%0)" :: "n"(NF + 2) : "memory");
    SB0(); BAR();
  }

  // ---- epilogue
#pragma unroll
  for (int i = 0; i < 8; ++i) {
    const int rb  = ((i & 4) ? 128 : 0) + wr * 64 + (i & 3) * 16;
    const int row = bm + rb + q * 4;
    const int orow = PADOUT ? (row + 3 + 6 * bbatch) : row;
#pragma unroll
    for (int j = 0; j < NF; ++j) {
      const int col = bn + j * 64 + wc * 16 + r16;
      const float bv = bias[col];
#pragma unroll
      for (int rr = 0; rr < 4; ++rr) {
        float v = acc[i][j][rr] + bv;
        if (ACT == 1) v = v / (1.f + __expf(-v));
        const size_t off = (size_t)(orow + rr) * N + col;
        if (OBF16) ((u16*)Cv)[off] = f2bf(v);
        else       ((float*)Cv)[off] = v;
      }
    }
  }
}

// ---------------- RG-LRU gate math (recomputed in both scan passes) ----------------
static __device__ __forceinline__ void gate_math(u16 ga_, u16 gi_, u16 h2_, float sp,
                                                 float& a, float& b) {
  const float ga = bf2f(ga_);
  const float gi = bf2f(gi_);
  const float h2 = bf2f(h2_);
  const float rr = 1.f / (1.f + __expf(-ga));
  const float ii = 1.f / (1.f + __expf(-gi));
  const float log_a = -8.f * rr * sp;
  a = __expf(log_a);
  const float e2 = __expf(2.f * log_a);
  b = sqrtf(fmaxf(1.f - e2, 0.f)) * ii * h2;
}

// ---------------- chunked scan: 3 passes (gate math fused into 1 and 3) ----------------
// gcat: [BL][2R] bf16 (ga | gi), h2b: [BL][R] bf16
__global__ void scan_pass1(const u16* __restrict__ gcat, const u16* __restrict__ h2b,
                           const float* __restrict__ lam,
                           float* __restrict__ Aprod, float* __restrict__ Hend) {
  int t = blockIdx.x * blockDim.x + threadIdx.x;   // over CHK_*B_*R_
  if (t >= CHK_ * B_ * R_) return;
  const int c = t / (B_ * R_), br = t % (B_ * R_);
  const int b = br / R_, r = br % R_;
  const float sp = log1pf(__expf(lam[r]));
  size_t rowbase = (size_t)b * L_ + (size_t)c * CLEN_;
  const u16* pg  = gcat + rowbase * (2 * R_) + r;
  const u16* ph2 = h2b + rowbase * R_ + r;
  float Ap = 1.f, h = 0.f;
  for (int l = 0; l < CLEN_; ++l) {
    float a, bb;
    gate_math(pg[0], pg[R_], ph2[0], sp, a, bb);
    Ap *= a;
    h = a * h + bb;
    pg += 2 * R_;
    ph2 += R_;
  }
  Aprod[t] = Ap;
  Hend[t]  = h;
}

__global__ void scan_pass2(const float* __restrict__ Aprod, float* __restrict__ Hend) {
  int br = blockIdx.x * blockDim.x + threadIdx.x;
  if (br >= B_ * R_) return;
  float h = Hend[br];                               // chunk 0 end state
  for (int c = 1; c < CHK_; ++c) {
    const int i = c * (B_ * R_) + br;
    h = Hend[i] + Aprod[i] * h;
    Hend[i] = h;
  }
}

__global__ void scan_pass3(const u16* __restrict__ gcat, const u16* __restrict__ h2b,
                           const float* __restrict__ lam,
                           const float* __restrict__ Hend, u16* __restrict__ hs) {
  int t = blockIdx.x * blockDim.x + threadIdx.x;
  if (t >= CHK_ * B_ * R_) return;
  const int c = t / (B_ * R_), br = t % (B_ * R_);
  const int b = br / R_, r = br % R_;
  const float sp = log1pf(__expf(lam[r]));
  float h = (c == 0) ? 0.f : Hend[(size_t)(c - 1) * (B_ * R_) + br];
  size_t rowbase = (size_t)b * L_ + (size_t)c * CLEN_;
  const u16* pg  = gcat + rowbase * (2 * R_) + r;
  const u16* ph2 = h2b + rowbase * R_ + r;
  u16* po = hs + rowbase * R_ + r;
  for (int l = 0; l < CLEN_; ++l) {
    float a, bb;
    gate_math(pg[0], pg[R_], ph2[0], sp, a, bb);
    h = a * h + bb;
    *po = f2bf(h);
    pg += 2 * R_;
    ph2 += R_;
    po += R_;
  }
}

// ---------------- launcher ----------------
extern "C" void kernel_launch(void* const* d_in, const int* in_sizes, int n_in,
                              void* d_out, int out_size, void* d_ws, size_t ws_size,
                              hipStream_t stream) {
  (void)in_sizes; (void)n_in; (void)out_size; (void)ws_size;
  const float* x   = (const float*)d_in[0];
  const float* w1  = (const float*)d_in[1];
  const float* b1  = (const float*)d_in[2];
  const float* cw  = (const float*)d_in[3];
  const float* cb  = (const float*)d_in[4];
  const float* wa  = (const float*)d_in[5];
  const float* ba  = (const float*)d_in[6];
  const float* wx  = (const float*)d_in[7];
  const float* bx  = (const float*)d_in[8];
  const float* lam = (const float*)d_in[9];
  const float* w2  = (const float*)d_in[10];
  const float* b2  = (const float*)d_in[11];

  char* ws = (char*)d_ws;
  size_t o = 0;
  auto alloc = [&](size_t bytes) { char* p = ws + o; o += (bytes + 255) & ~255ull; return p; };

  u16* w2b   = (u16*)alloc((size_t)D_ * R_ * 2);
  u16* wcatb = (u16*)alloc((size_t)2 * R_ * R_ * 2);   // [wa ; wx] -> [5120][2560]
  float* bcat = (float*)alloc((size_t)2 * R_ * 4);
  char* hsp = ws + o;                         // overlay: xb+w1b (dead after l1) = 44MB >= 42MB
  u16* xb  = (u16*)alloc((size_t)BL_ * D_ * 2);
  u16* w1b = (u16*)alloc((size_t)R_ * D_ * 2);
  u16* cwb = (u16*)alloc((size_t)4 * R_ * R_ * 2);
  u16* h1p = (u16*)alloc((size_t)B_ * LP_ * R_ * 2);   // padded h1
  u16* h2b = (u16*)alloc((size_t)BL_ * R_ * 2);
  u16* gcat = (u16*)alloc((size_t)BL_ * 2 * R_ * 2);   // [8192][5120] gates
  float* Aprod = (float*)alloc((size_t)CHK_ * B_ * R_ * 4);
  float* Hend  = (float*)alloc((size_t)CHK_ * B_ * R_ * 4);
  u16* hsb = (u16*)hsp;

  cvt_bf16<<<4096, 256, 0, stream>>>(x,  xb,  BL_ * D_);
  cvt_bf16<<<2048, 256, 0, stream>>>(w1, w1b, R_ * D_);
  cvt_bf16<<<2048, 256, 0, stream>>>(wa, wcatb, R_ * R_);
  cvt_bf16<<<2048, 256, 0, stream>>>(wx, wcatb + (size_t)R_ * R_, R_ * R_);
  cvt_bf16<<<2048, 256, 0, stream>>>(w2, w2b, D_ * R_);
  cvt_convw<<<(R_ * R_ + 255) / 256, 256, 0, stream>>>(cw, cwb);
  zero_pads<<<(24 * R_ + 255) / 256, 256, 0, stream>>>(h1p);
  cat_bias<<<(2 * R_ + 255) / 256, 256, 0, stream>>>(ba, bx, bcat);

  // linear1 + silu -> padded h1 (rows +3+6*batch): grid 32 x 10 = 320
  gemm256<2048, 1, 1, 1, 1><<<320, 512, 0, stream>>>(xb, w1b, b1, h1p, R_, 32);
  // temporal conv: K' = 4*R GEMM over padded h1: grid 32 x 10 = 320
  gemm256<2560, 4, 0, 1, 0><<<320, 512, 0, stream>>>(h1p, cwb, cb, h2b, R_, 32);
  // both gates in ONE GEMM: B = [wa;wx] (5120 x 2560), C = gcat [8192][5120]: 32 x 20 = 640
  gemm256<2560, 1, 0, 1, 0><<<640, 512, 0, stream>>>(h2b, wcatb, bcat, gcat, 2 * R_, 32);
  // linear recurrence (chunked, 3 passes; gate math fused into 1 and 3)
  scan_pass1<<<(CHK_ * B_ * R_ + 255) / 256, 256, 0, stream>>>(gcat, h2b, lam, Aprod, Hend);
  scan_pass2<<<(B_ * R_ + 255) / 256, 256, 0, stream>>>(Aprod, Hend);
  scan_pass3<<<(CHK_ * B_ * R_ + 255) / 256, 256, 0, stream>>>(gcat, h2b, lam, Hend, hsb);
  // linear2 -> d_out (fp32): grid 32 x 8 = 256 exact
  gemm256<2560, 1, 0, 0, 0><<<256, 512, 0, stream>>>(hsb, w2b, b2, d_out, D_, 32);
}